// Round 5
// baseline (273.143 us; speedup 1.0000x reference)
//
#include <hip/hip_runtime.h>
#include <stdint.h>

#define BATCH 8
#define NN 262144
#define K_PRE 6000
#define NPROP 1000
#define NMS_THR 0.7f
#define CAND_CAP 8192
#define PREFIX 2048
#define NB1 16384
#define NB2 4096

// meta u32 indices
#define MT_T2 0        // [0..7]   final threshold (read-only after thresh2)
#define MT_KEPT 16     // [16..23] kept count per batch
#define MT_T1 24       // [24..31] coarse bucket
#define MT_CUM 32      // [32..39] cum count above coarse bucket
#define MT_CNT(b) (64 + 32*(b))   // padded counters, 128B apart

// workspace layout (bytes)
#define HIST1_OFF 0                                   // BATCH*NB1*4 = 524288
#define HIST2_OFF (HIST1_OFF + BATCH*NB1*4)           // + BATCH*NB2*4 = 131072
#define META_OFF  (HIST2_OFF + BATCH*NB2*4)           // 2048 B
#define CAND_OFF  (META_OFF + 2048)
#define BOXES_OFF (CAND_OFF + BATCH*CAND_CAP*8)       // BATCH*K_PRE*16
#define MASK_OFF  (BOXES_OFF + BATCH*K_PRE*16)        // BATCH*PREFIX*64*4 = 4 MB
#define KIDX_OFF  (MASK_OFF + (size_t)BATCH*PREFIX*64*4)
#define WS_NEED   (KIDX_OFF + BATCH*NPROP*4)

// Bank-conflict-killing swizzle for the bitonic arrays (u32, 32 banks):
// every bitonic stride j=2^b (b<5) confines logical indices to the subcube
// with bit b fixed; the 64-lane footprint spans 4 consecutive (i>>5) groups.
// M is chosen so each low bit is set in exactly 2 of the 4 group masks ->
// every phase spreads 2/2 across the missing bit => <=2-way (free).
__device__ __forceinline__ int SWZ(int i) {
    return i ^ (int)((0x1E150B00u >> (((i >> 5) & 3) * 8)) & 0xFFu);
}

__device__ __forceinline__ uint32_t fkey(float f) {
    uint32_t b = __float_as_uint(f);
    return b ^ (uint32_t)(((int32_t)b >> 31) | 0x80000000u);
}

__global__ void k_zero(uint32_t* h) {
    const int i = blockIdx.x * 256 + threadIdx.x;
    if (i < BATCH * (NB1 + NB2)) h[i] = 0;
}

// 512 blocks = 64 per batch; each block: 2048 float4 (= 4096 elements).
__global__ __launch_bounds__(256) void k_hist(const float4* __restrict__ probs4,
                                              uint32_t* __restrict__ hist) {
    __shared__ uint32_t h[NB1];
    for (int i = threadIdx.x; i < NB1; i += 256) h[i] = 0;
    __syncthreads();
    const int b = blockIdx.x >> 6;
    const int s = blockIdx.x & 63;
    const float4* p = probs4 + (size_t)b * (NN / 2) + (size_t)s * 2048;
    for (int i = threadIdx.x; i < 2048; i += 256) {
        const float4 v = p[i];
        atomicAdd(&h[fkey(v.y) >> 18], 1u);
        atomicAdd(&h[fkey(v.w) >> 18], 1u);
    }
    __syncthreads();
    uint32_t* gh = hist + (size_t)b * NB1;
    for (int i = threadIdx.x; i < NB1; i += 256)
        if (h[i]) atomicAdd(&gh[i], h[i]);
}

__global__ __launch_bounds__(256) void k_thresh(const uint32_t* __restrict__ hist,
                                                uint32_t* meta) {
    const int b = blockIdx.x;
    const uint32_t* gh = hist + (size_t)b * NB1;
    __shared__ uint32_t part[256];
    const int t = threadIdx.x;
    uint32_t s = 0;
    const int hi = NB1 - 64 * t;
    for (int i = hi - 64; i < hi; ++i) s += gh[i];
    part[t] = s;
    __syncthreads();
    if (t == 0) {
        uint32_t cum = 0;
        int strip = 0;
        for (; strip < 256; ++strip) {
            if (cum + part[strip] >= (uint32_t)K_PRE) break;
            cum += part[strip];
        }
        int t1 = 0;
        if (strip < 256) {
            const int top = NB1 - 64 * strip;
            int i = top - 1;
            for (; i >= top - 64; --i) {
                const uint32_t c = gh[i];
                if (cum + c >= (uint32_t)K_PRE) break;
                cum += c;
            }
            if (i < top - 64) i = top - 64;
            t1 = i;
        }
        meta[MT_T1 + b] = (uint32_t)t1;
        meta[MT_CUM + b] = cum;  // count strictly above bucket t1
    }
}

// 2048 blocks = 256 per batch; ~8k matches per batch spread over 4096 buckets.
__global__ __launch_bounds__(256) void k_hist2(const float4* __restrict__ probs4,
                                               const uint32_t* __restrict__ meta,
                                               uint32_t* __restrict__ hist2) {
    const int b = blockIdx.x >> 8;
    const int s = blockIdx.x & 255;
    const uint32_t t1 = meta[MT_T1 + b];
    const float4* p = probs4 + (size_t)b * (NN / 2) + (size_t)s * 512;
    uint32_t* gh = hist2 + (size_t)b * NB2;
    for (int i = threadIdx.x; i < 512; i += 256) {
        const float4 v = p[i];
        const uint32_t u1 = fkey(v.y);
        const uint32_t u2 = fkey(v.w);
        if ((u1 >> 18) == t1) atomicAdd(&gh[(u1 >> 6) & 0xFFFu], 1u);
        if ((u2 >> 18) == t1) atomicAdd(&gh[(u2 >> 6) & 0xFFFu], 1u);
    }
}

__global__ __launch_bounds__(256) void k_thresh2(const uint32_t* __restrict__ hist2,
                                                 uint32_t* meta) {
    const int b = blockIdx.x;
    const uint32_t* gh = hist2 + (size_t)b * NB2;
    __shared__ uint32_t part[256];
    const int t = threadIdx.x;
    uint32_t s = 0;
    const int hi = NB2 - 16 * t;
    for (int i = hi - 16; i < hi; ++i) s += gh[i];
    part[t] = s;
    __syncthreads();
    if (t == 0) {
        const uint32_t t1 = meta[MT_T1 + b];
        uint32_t cum = meta[MT_CUM + b];
        int strip = 0;
        for (; strip < 256; ++strip) {
            if (cum + part[strip] >= (uint32_t)K_PRE) break;
            cum += part[strip];
        }
        int sub = 0;
        if (strip < 256) {
            const int top = NB2 - 16 * strip;
            int i = top - 1;
            for (; i >= top - 16; --i) {
                const uint32_t c = gh[i];
                if (cum + c >= (uint32_t)K_PRE) break;
                cum += c;
            }
            if (i < top - 16) i = top - 16;
            sub = i;
        }
        meta[MT_T2 + b] = (t1 << 18) | ((uint32_t)sub << 6);
        meta[MT_CNT(b)] = 0;
        meta[MT_KEPT + b] = 0;
    }
}

// 2048 blocks = 256 per batch. Contention-free: LDS stash + ONE padded global
// atomic per block. cand[] slot order is irrelevant (key carries full order).
__global__ __launch_bounds__(256) void k_compact(const float4* __restrict__ probs4,
                                                 const uint32_t* __restrict__ meta,
                                                 uint32_t* cnt_meta, uint64_t* __restrict__ cand) {
    __shared__ uint64_t stash[1024];
    __shared__ uint32_t lcnt, lbase;
    const int b = blockIdx.x >> 8;
    const int s = blockIdx.x & 255;
    const uint32_t T = meta[MT_T2 + b];
    if (threadIdx.x == 0) lcnt = 0;
    __syncthreads();
    const float4* p = probs4 + (size_t)b * (NN / 2) + (size_t)s * 512;
    const uint32_t base_n = (uint32_t)s * 1024;
    for (int i = threadIdx.x; i < 512; i += 256) {
        const float4 v = p[i];
        const uint32_t u1 = fkey(v.y);
        const uint32_t u2 = fkey(v.w);
        if (u1 >= T) {
            const uint32_t pos = atomicAdd(&lcnt, 1u);
            const uint32_t n = base_n + 2u * (uint32_t)i;
            stash[pos] = ((uint64_t)u1 << 32) | (uint32_t)(~n);
        }
        if (u2 >= T) {
            const uint32_t pos = atomicAdd(&lcnt, 1u);
            const uint32_t n = base_n + 2u * (uint32_t)i + 1u;
            stash[pos] = ((uint64_t)u2 << 32) | (uint32_t)(~n);
        }
    }
    __syncthreads();
    if (threadIdx.x == 0) lbase = atomicAdd(&cnt_meta[MT_CNT(b)], lcnt);
    __syncthreads();
    uint64_t* cb = cand + (size_t)b * CAND_CAP;
    const uint32_t n_loc = lcnt, base = lbase;
    for (uint32_t i = threadIdx.x; i < n_loc; i += 256) {
        const uint32_t pos = base + i;
        if (pos < CAND_CAP) cb[pos] = stash[i];
    }
}

// Bitonic sort of 8192 x u64 keys, stored as swizzled hi/lo u32 LDS arrays
// (bank-conflict-free; see SWZ), then decode top-6000 boxes.
__global__ __launch_bounds__(1024) void k_sortdecode(const uint64_t* __restrict__ cand,
        const uint32_t* __restrict__ meta,
        const float4* __restrict__ bbox, const float4* __restrict__ anch,
        float4* __restrict__ boxes) {
    __shared__ uint32_t shi[CAND_CAP];
    __shared__ uint32_t slo[CAND_CAP];
    const int b = blockIdx.x;
    const uint32_t m = min(meta[MT_CNT(b)], (uint32_t)CAND_CAP);
    const uint64_t* c = cand + (size_t)b * CAND_CAP;
    for (int i = threadIdx.x; i < CAND_CAP; i += 1024) {
        const uint64_t k = (i < (int)m) ? c[i] : 0ull;
        const int s = SWZ(i);
        shi[s] = (uint32_t)(k >> 32);
        slo[s] = (uint32_t)k;
    }
    __syncthreads();
    for (int k = 2; k <= CAND_CAP; k <<= 1) {
        for (int j = k >> 1; j > 0; j >>= 1) {
            for (int t = threadIdx.x; t < CAND_CAP / 2; t += 1024) {
                const int i = ((t & ~(j - 1)) << 1) | (t & (j - 1));
                const int p = i | j;
                const int si = SWZ(i), sp = SWZ(p);
                const uint32_t ahi = shi[si], bhi = shi[sp];
                const uint32_t alo = slo[si], blo = slo[sp];
                const bool altb = (ahi < bhi) || (ahi == bhi && alo < blo);
                const bool up = ((i & k) == 0);
                if (altb == up) {
                    shi[si] = bhi; slo[si] = blo;
                    shi[sp] = ahi; slo[sp] = alo;
                }
            }
            __syncthreads();
        }
    }
    for (int r = threadIdx.x; r < K_PRE; r += 1024) {
        const uint32_t n = ~slo[SWZ(r)];
        const float4 a = anch[(size_t)b * NN + n];
        const float4 d = bbox[(size_t)b * NN + n];
        float h = a.z - a.x, w = a.w - a.y;
        const float cy0 = a.x + 0.5f * h + d.x * 0.1f * h;
        const float cx0 = a.y + 0.5f * w + d.y * 0.1f * w;
        h = h * expf(d.z * 0.2f);
        w = w * expf(d.w * 0.2f);
        float4 o;
        o.x = fminf(fmaxf(cy0 - 0.5f * h, 0.0f), 1.0f);
        o.y = fminf(fmaxf(cx0 - 0.5f * w, 0.0f), 1.0f);
        o.z = fminf(fmaxf(cy0 + 0.5f * h, 0.0f), 1.0f);
        o.w = fminf(fmaxf(cx0 + 0.5f * w, 0.0f), 1.0f);
        boxes[(size_t)b * K_PRE + r] = o;
    }
}

__global__ __launch_bounds__(256) void k_matrix(const float4* __restrict__ boxes,
                                                uint32_t* __restrict__ mask) {
    const int blk = blockIdx.x;
    const int b = blk >> 10;
    const int tile = blk & 1023;
    const int ti = tile >> 5, tj = tile & 31;
    __shared__ float4 rb[64], cb[64];
    __shared__ uint32_t wbits[128];
    const float4* bx = boxes + (size_t)b * K_PRE;
    const int t = threadIdx.x;
    if (t < 64) rb[t] = bx[ti * 64 + t];
    else if (t < 128) cb[t - 64] = bx[tj * 64 + (t - 64)];
    if (t < 128) wbits[t] = 0;
    __syncthreads();
    const int r = t >> 2;
    const int cq = t & 3;
    const float4 a = rb[r];
    const float areaA = (a.z - a.x) * (a.w - a.y);
    uint32_t bits = 0;
#pragma unroll
    for (int jj = 0; jj < 16; ++jj) {
        const float4 cc = cb[cq * 16 + jj];
        const float yy1 = fmaxf(a.x, cc.x), xx1 = fmaxf(a.y, cc.y);
        const float yy2 = fminf(a.z, cc.z), xx2 = fminf(a.w, cc.w);
        const float inter = fmaxf(yy2 - yy1, 0.0f) * fmaxf(xx2 - xx1, 0.0f);
        const float areaC = (cc.z - cc.x) * (cc.w - cc.y);
        const float uni = fmaxf(areaA + areaC - inter, 1e-8f);
        if (inter / uni > NMS_THR) bits |= (1u << jj);
    }
    atomicOr(&wbits[r * 2 + (cq >> 1)], bits << ((cq & 1) * 16));
    __syncthreads();
    if (t < 128) {
        const int rr = t >> 1, ww = t & 1;
        mask[((size_t)b * PREFIX + ti * 64 + rr) * 64 + tj * 2 + ww] = wbits[rr * 2 + ww];
    }
}

// Greedy NMS bit-scan over the 2048x2048 suppression matrix.
__global__ __launch_bounds__(256) void k_greedy(const uint32_t* __restrict__ mask,
                                                uint32_t* meta, uint32_t* __restrict__ kept_idx) {
    __shared__ uint32_t lbuf[2][256 * 64];   // 2 x 64 KB
    __shared__ uint32_t skept[8];
    const int b = blockIdx.x;
    const int lane = threadIdx.x & 63;
    const int wave = threadIdx.x >> 6;
    const uint32_t* mrow = mask + (size_t)b * PREFIX * 64;

    {
        const uint4* s4 = (const uint4*)mrow;
        uint4* d4 = (uint4*)lbuf[0];
        for (int idx = threadIdx.x; idx < 4096; idx += 256) d4[idx] = s4[idx];
    }
    __syncthreads();

    uint32_t supp = 0;   // lane l: suppression bits for columns [32l, 32l+32)
    uint32_t kept = 0;

    for (int c = 0; c < PREFIX / 256; ++c) {
        if (wave > 0) {
            if (c + 1 < PREFIX / 256) {
                const uint4* s4 = (const uint4*)(mrow + (size_t)(c + 1) * 256 * 64);
                uint4* d4 = (uint4*)lbuf[(c + 1) & 1];
                for (int idx = threadIdx.x - 64; idx < 4096; idx += 192) d4[idx] = s4[idx];
            }
        } else {
            const uint32_t* L = lbuf[c & 1];
            for (int g = 0; g < 8; ++g) {
                if (kept >= NPROP) break;
                const int grow = c * 256 + g * 32;
                const int w = grow >> 5;
                uint32_t rbuf[32];
#pragma unroll
                for (int q = 0; q < 32; ++q) rbuf[q] = L[(g * 32 + q) * 64 + lane];
                uint32_t sw = __builtin_amdgcn_readlane(supp, w);
#pragma unroll
                for (int q = 0; q < 32; ++q) {
                    if (kept < NPROP && !((sw >> q) & 1u)) {
                        if (lane == 0) kept_idx[(size_t)b * NPROP + kept] = (uint32_t)(grow + q);
                        supp |= rbuf[q];
                        sw |= __builtin_amdgcn_readlane(rbuf[q], w);
                        ++kept;
                    }
                }
            }
            if (lane == 0) skept[c] = kept;
        }
        __syncthreads();
        if (skept[c] >= NPROP) break;
    }
    if (wave == 0 && lane == 0) meta[MT_KEPT + b] = kept;
}

__global__ __launch_bounds__(1024) void k_finish(const float4* __restrict__ boxes,
        uint32_t* meta, uint32_t* kept_idx, float4* __restrict__ out) {
    const int b = blockIdx.x;
    const float4* bx = boxes + (size_t)b * K_PRE;
    __shared__ float4 kb[NPROP];
    __shared__ uint32_t sflag;
    uint32_t kept = meta[MT_KEPT + b];
    if (kept < NPROP) {
        for (uint32_t k = threadIdx.x; k < kept; k += 1024)
            kb[k] = bx[kept_idx[(size_t)b * NPROP + k]];
        __syncthreads();
        for (int i = PREFIX; i < K_PRE && kept < NPROP; ++i) {
            if (threadIdx.x == 0) sflag = 0;
            __syncthreads();
            const float4 c = bx[i];
            const float areaC = (c.z - c.x) * (c.w - c.y);
            bool sup = false;
            for (uint32_t k = threadIdx.x; k < kept; k += 1024) {
                const float4 a = kb[k];
                const float yy1 = fmaxf(c.x, a.x), xx1 = fmaxf(c.y, a.y);
                const float yy2 = fminf(c.z, a.z), xx2 = fminf(c.w, a.w);
                const float inter = fmaxf(yy2 - yy1, 0.0f) * fmaxf(xx2 - xx1, 0.0f);
                const float areaA = (a.z - a.x) * (a.w - a.y);
                const float uni = fmaxf(areaC + areaA - inter, 1e-8f);
                if (inter / uni > NMS_THR) { sup = true; break; }
            }
            if (sup) atomicOr(&sflag, 1u);
            __syncthreads();
            if (sflag == 0) {
                if (threadIdx.x == 0) {
                    kept_idx[(size_t)b * NPROP + kept] = (uint32_t)i;
                    kb[kept] = c;
                }
                ++kept;
            }
            __syncthreads();
        }
        if (threadIdx.x == 0) meta[MT_KEPT + b] = kept;
    }
    __syncthreads();
    for (uint32_t k = threadIdx.x; k < NPROP; k += 1024) {
        float4 v = make_float4(0.f, 0.f, 0.f, 0.f);
        if (k < kept) v = bx[kept_idx[(size_t)b * NPROP + k]];
        out[(size_t)b * NPROP + k] = v;
    }
}

extern "C" void kernel_launch(void* const* d_in, const int* in_sizes, int n_in,
                              void* d_out, int out_size, void* d_ws, size_t ws_size,
                              hipStream_t stream) {
    const float4* probs4 = (const float4*)d_in[0];
    const float4* bbox   = (const float4*)d_in[1];
    const float4* anch   = (const float4*)d_in[2];
    char* ws = (char*)d_ws;
    if (ws_size < (size_t)WS_NEED) return;
    uint32_t* hist1 = (uint32_t*)(ws + HIST1_OFF);
    uint32_t* hist2 = (uint32_t*)(ws + HIST2_OFF);
    uint32_t* meta  = (uint32_t*)(ws + META_OFF);
    uint64_t* cand  = (uint64_t*)(ws + CAND_OFF);
    float4*   boxes = (float4*)(ws + BOXES_OFF);
    uint32_t* mask  = (uint32_t*)(ws + MASK_OFF);
    uint32_t* kidx  = (uint32_t*)(ws + KIDX_OFF);

    k_zero<<<dim3((BATCH * (NB1 + NB2) + 255) / 256), dim3(256), 0, stream>>>(hist1);
    k_hist<<<dim3(512), dim3(256), 0, stream>>>(probs4, hist1);
    k_thresh<<<dim3(BATCH), dim3(256), 0, stream>>>(hist1, meta);
    k_hist2<<<dim3(2048), dim3(256), 0, stream>>>(probs4, meta, hist2);
    k_thresh2<<<dim3(BATCH), dim3(256), 0, stream>>>(hist2, meta);
    k_compact<<<dim3(2048), dim3(256), 0, stream>>>(probs4, meta, meta, cand);
    k_sortdecode<<<dim3(BATCH), dim3(1024), 0, stream>>>(cand, meta, bbox, anch, boxes);
    k_matrix<<<dim3(BATCH * 1024), dim3(256), 0, stream>>>(boxes, mask);
    k_greedy<<<dim3(BATCH), dim3(256), 0, stream>>>(mask, meta, kidx);
    k_finish<<<dim3(BATCH), dim3(1024), 0, stream>>>(boxes, meta, kidx, (float4*)d_out);
}

// Round 6
// 215.021 us; speedup vs baseline: 1.2703x; 1.2703x over previous
//
#include <hip/hip_runtime.h>
#include <stdint.h>

#define BATCH 8
#define NN 262144
#define K_PRE 6000
#define NPROP 1000
#define NMS_THR 0.7f
#define CAND_CAP 8192
#define PREFIX 2048
#define NB1 16384
#define NB2 4096

// meta u32 indices
#define MT_T2 0        // [0..7]   final threshold (read-only after thresh2)
#define MT_KEPT 16     // [16..23] kept count per batch
#define MT_T1 24       // [24..31] coarse bucket
#define MT_CUM 32      // [32..39] cum count above coarse bucket
#define MT_CNT(b) (64 + 32*(b))   // padded counters, 128B apart

// workspace layout (bytes)
#define HIST1_OFF 0                                   // BATCH*NB1*4 = 524288
#define HIST2_OFF (HIST1_OFF + BATCH*NB1*4)           // + BATCH*NB2*4 = 131072
#define META_OFF  (HIST2_OFF + BATCH*NB2*4)           // 2048 B
#define CAND_OFF  (META_OFF + 2048)
#define BOXES_OFF (CAND_OFF + BATCH*CAND_CAP*8)       // BATCH*K_PRE*16
#define MASK_OFF  (BOXES_OFF + BATCH*K_PRE*16)        // BATCH*PREFIX*64*4 = 4 MB
#define KIDX_OFF  (MASK_OFF + (size_t)BATCH*PREFIX*64*4)
#define WS_NEED   (KIDX_OFF + BATCH*NPROP*4)

__device__ __forceinline__ uint32_t fkey(float f) {
    uint32_t b = __float_as_uint(f);
    return b ^ (uint32_t)(((int32_t)b >> 31) | 0x80000000u);
}

__global__ void k_zero(uint32_t* h) {
    const int i = blockIdx.x * 256 + threadIdx.x;
    if (i < BATCH * (NB1 + NB2)) h[i] = 0;
}

// 512 blocks = 64 per batch; each block: 2048 float4 (= 4096 elements).
__global__ __launch_bounds__(256) void k_hist(const float4* __restrict__ probs4,
                                              uint32_t* __restrict__ hist) {
    __shared__ uint32_t h[NB1];
    for (int i = threadIdx.x; i < NB1; i += 256) h[i] = 0;
    __syncthreads();
    const int b = blockIdx.x >> 6;
    const int s = blockIdx.x & 63;
    const float4* p = probs4 + (size_t)b * (NN / 2) + (size_t)s * 2048;
    for (int i = threadIdx.x; i < 2048; i += 256) {
        const float4 v = p[i];
        atomicAdd(&h[fkey(v.y) >> 18], 1u);
        atomicAdd(&h[fkey(v.w) >> 18], 1u);
    }
    __syncthreads();
    uint32_t* gh = hist + (size_t)b * NB1;
    for (int i = threadIdx.x; i < NB1; i += 256)
        if (h[i]) atomicAdd(&gh[i], h[i]);
}

__global__ __launch_bounds__(256) void k_thresh(const uint32_t* __restrict__ hist,
                                                uint32_t* meta) {
    const int b = blockIdx.x;
    const uint32_t* gh = hist + (size_t)b * NB1;
    __shared__ uint32_t part[256];
    const int t = threadIdx.x;
    uint32_t s = 0;
    const int hi = NB1 - 64 * t;
    for (int i = hi - 64; i < hi; ++i) s += gh[i];
    part[t] = s;
    __syncthreads();
    if (t == 0) {
        uint32_t cum = 0;
        int strip = 0;
        for (; strip < 256; ++strip) {
            if (cum + part[strip] >= (uint32_t)K_PRE) break;
            cum += part[strip];
        }
        int t1 = 0;
        if (strip < 256) {
            const int top = NB1 - 64 * strip;
            int i = top - 1;
            for (; i >= top - 64; --i) {
                const uint32_t c = gh[i];
                if (cum + c >= (uint32_t)K_PRE) break;
                cum += c;
            }
            if (i < top - 64) i = top - 64;
            t1 = i;
        }
        meta[MT_T1 + b] = (uint32_t)t1;
        meta[MT_CUM + b] = cum;  // count strictly above bucket t1
    }
}

// 2048 blocks = 256 per batch; ~8k matches per batch spread over 4096 buckets.
__global__ __launch_bounds__(256) void k_hist2(const float4* __restrict__ probs4,
                                               const uint32_t* __restrict__ meta,
                                               uint32_t* __restrict__ hist2) {
    const int b = blockIdx.x >> 8;
    const int s = blockIdx.x & 255;
    const uint32_t t1 = meta[MT_T1 + b];
    const float4* p = probs4 + (size_t)b * (NN / 2) + (size_t)s * 512;
    uint32_t* gh = hist2 + (size_t)b * NB2;
    for (int i = threadIdx.x; i < 512; i += 256) {
        const float4 v = p[i];
        const uint32_t u1 = fkey(v.y);
        const uint32_t u2 = fkey(v.w);
        if ((u1 >> 18) == t1) atomicAdd(&gh[(u1 >> 6) & 0xFFFu], 1u);
        if ((u2 >> 18) == t1) atomicAdd(&gh[(u2 >> 6) & 0xFFFu], 1u);
    }
}

__global__ __launch_bounds__(256) void k_thresh2(const uint32_t* __restrict__ hist2,
                                                 uint32_t* meta) {
    const int b = blockIdx.x;
    const uint32_t* gh = hist2 + (size_t)b * NB2;
    __shared__ uint32_t part[256];
    const int t = threadIdx.x;
    uint32_t s = 0;
    const int hi = NB2 - 16 * t;
    for (int i = hi - 16; i < hi; ++i) s += gh[i];
    part[t] = s;
    __syncthreads();
    if (t == 0) {
        const uint32_t t1 = meta[MT_T1 + b];
        uint32_t cum = meta[MT_CUM + b];
        int strip = 0;
        for (; strip < 256; ++strip) {
            if (cum + part[strip] >= (uint32_t)K_PRE) break;
            cum += part[strip];
        }
        int sub = 0;
        if (strip < 256) {
            const int top = NB2 - 16 * strip;
            int i = top - 1;
            for (; i >= top - 16; --i) {
                const uint32_t c = gh[i];
                if (cum + c >= (uint32_t)K_PRE) break;
                cum += c;
            }
            if (i < top - 16) i = top - 16;
            sub = i;
        }
        meta[MT_T2 + b] = (t1 << 18) | ((uint32_t)sub << 6);
        meta[MT_CNT(b)] = 0;
        meta[MT_KEPT + b] = 0;
    }
}

// 2048 blocks = 256 per batch. Contention-free: LDS stash + ONE padded global
// atomic per block. cand[] slot order is irrelevant (key carries full order).
__global__ __launch_bounds__(256) void k_compact(const float4* __restrict__ probs4,
                                                 const uint32_t* __restrict__ meta,
                                                 uint32_t* cnt_meta, uint64_t* __restrict__ cand) {
    __shared__ uint64_t stash[1024];
    __shared__ uint32_t lcnt, lbase;
    const int b = blockIdx.x >> 8;
    const int s = blockIdx.x & 255;
    const uint32_t T = meta[MT_T2 + b];
    if (threadIdx.x == 0) lcnt = 0;
    __syncthreads();
    const float4* p = probs4 + (size_t)b * (NN / 2) + (size_t)s * 512;
    const uint32_t base_n = (uint32_t)s * 1024;
    for (int i = threadIdx.x; i < 512; i += 256) {
        const float4 v = p[i];
        const uint32_t u1 = fkey(v.y);
        const uint32_t u2 = fkey(v.w);
        if (u1 >= T) {
            const uint32_t pos = atomicAdd(&lcnt, 1u);
            const uint32_t n = base_n + 2u * (uint32_t)i;
            stash[pos] = ((uint64_t)u1 << 32) | (uint32_t)(~n);
        }
        if (u2 >= T) {
            const uint32_t pos = atomicAdd(&lcnt, 1u);
            const uint32_t n = base_n + 2u * (uint32_t)i + 1u;
            stash[pos] = ((uint64_t)u2 << 32) | (uint32_t)(~n);
        }
    }
    __syncthreads();
    if (threadIdx.x == 0) lbase = atomicAdd(&cnt_meta[MT_CNT(b)], lcnt);
    __syncthreads();
    uint64_t* cb = cand + (size_t)b * CAND_CAP;
    const uint32_t n_loc = lcnt, base = lbase;
    for (uint32_t i = threadIdx.x; i < n_loc; i += 256) {
        const uint32_t pos = base + i;
        if (pos < CAND_CAP) cb[pos] = stash[i];
    }
}

// ---- register-blocked bitonic sort of 8192 u64 keys (hi/lo u32 split) ----
// skew keeps all round access patterns <=2-way bank aliased while preserving
// 16B alignment of consecutive-8 rounds (skew step is a multiple of 4).
#define SK(i) ((i) + 4 * ((i) >> 5))
#define SORT_PAD (CAND_CAP + 4 * (CAND_CAP / 32))

#define CE(x, y, up) { \
    const bool lt_ = (hi[x] < hi[y]) || (hi[x] == hi[y] && lo[x] < lo[y]); \
    if (lt_ == (up)) { \
        uint32_t th_ = hi[x]; hi[x] = hi[y]; hi[y] = th_; \
        uint32_t tl_ = lo[x]; lo[x] = lo[y]; lo[y] = tl_; \
    } \
}

#define MERGE8_L3(up) \
    CE(0,4,up) CE(1,5,up) CE(2,6,up) CE(3,7,up) \
    CE(0,2,up) CE(1,3,up) CE(4,6,up) CE(5,7,up) \
    CE(0,1,up) CE(2,3,up) CE(4,5,up) CE(6,7,up)

// one LDS round-trip, 3 levels (strides J0, J0/2, J0/4) of stage K
#define ROUND3(J0, K) { \
    const int base = (t & ((J0)/4 - 1)) | ((t / ((J0)/4)) * ((J0)*2)); \
    const bool up = ((base & (K)) == 0); \
    int pix[8]; \
    _Pragma("unroll") \
    for (int e = 0; e < 8; ++e) { \
        const int ix = base | ((e & 1) ? ((J0)/4) : 0) | ((e & 2) ? ((J0)/2) : 0) | ((e & 4) ? (J0) : 0); \
        pix[e] = SK(ix); \
        hi[e] = shi[pix[e]]; lo[e] = slo[pix[e]]; \
    } \
    MERGE8_L3(up) \
    _Pragma("unroll") \
    for (int e = 0; e < 8; ++e) { shi[pix[e]] = hi[e]; slo[pix[e]] = lo[e]; } \
    __syncthreads(); \
}

// consecutive-8 round: remaining NLEV in {1,2,3} lowest levels of stage K
#define CONSECR(K, NLEV) { \
    const int base = t << 3; \
    const int pb = SK(base); \
    _Pragma("unroll") \
    for (int e = 0; e < 8; ++e) { hi[e] = shi[pb + e]; lo[e] = slo[pb + e]; } \
    const bool up = ((base & (K)) == 0); \
    if ((NLEV) >= 3) { CE(0,4,up) CE(1,5,up) CE(2,6,up) CE(3,7,up) } \
    if ((NLEV) >= 2) { CE(0,2,up) CE(1,3,up) CE(4,6,up) CE(5,7,up) } \
    CE(0,1,up) CE(2,3,up) CE(4,5,up) CE(6,7,up) \
    _Pragma("unroll") \
    for (int e = 0; e < 8; ++e) { shi[pb + e] = hi[e]; slo[pb + e] = lo[e]; } \
    __syncthreads(); \
}

__global__ __launch_bounds__(1024) void k_sortdecode(const uint64_t* __restrict__ cand,
        const uint32_t* __restrict__ meta,
        const float4* __restrict__ bbox, const float4* __restrict__ anch,
        float4* __restrict__ boxes) {
    __shared__ uint32_t shi[SORT_PAD];
    __shared__ uint32_t slo[SORT_PAD];
    const int b = blockIdx.x;
    const uint32_t m = min(meta[MT_CNT(b)], (uint32_t)CAND_CAP);
    const uint64_t* c = cand + (size_t)b * CAND_CAP;
    const int t = threadIdx.x;
    uint32_t hi[8], lo[8];

    // round 0: global -> regs, full bitonic sort-8 (stages k=2,4,8), -> LDS
    {
        const int base = t << 3;
#pragma unroll
        for (int e = 0; e < 8; ++e) {
            const int i = base + e;
            const uint64_t k = (i < (int)m) ? c[i] : 0ull;
            hi[e] = (uint32_t)(k >> 32);
            lo[e] = (uint32_t)k;
        }
        // k=2
        CE(0,1,true) CE(2,3,false) CE(4,5,true) CE(6,7,false)
        // k=4
        CE(0,2,true)  CE(1,3,true)  CE(0,1,true)  CE(2,3,true)
        CE(4,6,false) CE(5,7,false) CE(4,5,false) CE(6,7,false)
        // k=8
        const bool u8 = ((t & 1) == 0);
        CE(0,4,u8) CE(1,5,u8) CE(2,6,u8) CE(3,7,u8)
        CE(0,2,u8) CE(1,3,u8) CE(4,6,u8) CE(5,7,u8)
        CE(0,1,u8) CE(2,3,u8) CE(4,5,u8) CE(6,7,u8)
        const int pb = SK(base);
#pragma unroll
        for (int e = 0; e < 8; ++e) { shi[pb + e] = hi[e]; slo[pb + e] = lo[e]; }
        __syncthreads();
    }

    ROUND3(8, 16)        CONSECR(16, 1)
    ROUND3(16, 32)       CONSECR(32, 2)
    ROUND3(32, 64)       CONSECR(64, 3)
    ROUND3(64, 128)      ROUND3(8, 128)     CONSECR(128, 1)
    ROUND3(128, 256)     ROUND3(16, 256)    CONSECR(256, 2)
    ROUND3(256, 512)     ROUND3(32, 512)    CONSECR(512, 3)
    ROUND3(512, 1024)    ROUND3(64, 1024)   ROUND3(8, 1024)   CONSECR(1024, 1)
    ROUND3(1024, 2048)   ROUND3(128, 2048)  ROUND3(16, 2048)  CONSECR(2048, 2)
    ROUND3(2048, 4096)   ROUND3(256, 4096)  ROUND3(32, 4096)  CONSECR(4096, 3)
    ROUND3(4096, 8192)   ROUND3(512, 8192)  ROUND3(64, 8192)  ROUND3(8, 8192)  CONSECR(8192, 1)

    for (int r = t; r < K_PRE; r += 1024) {
        const uint32_t n = ~slo[SK(r)];
        const float4 a = anch[(size_t)b * NN + n];
        const float4 d = bbox[(size_t)b * NN + n];
        float h = a.z - a.x, w = a.w - a.y;
        const float cy0 = a.x + 0.5f * h + d.x * 0.1f * h;
        const float cx0 = a.y + 0.5f * w + d.y * 0.1f * w;
        h = h * expf(d.z * 0.2f);
        w = w * expf(d.w * 0.2f);
        float4 o;
        o.x = fminf(fmaxf(cy0 - 0.5f * h, 0.0f), 1.0f);
        o.y = fminf(fmaxf(cx0 - 0.5f * w, 0.0f), 1.0f);
        o.z = fminf(fmaxf(cy0 + 0.5f * h, 0.0f), 1.0f);
        o.w = fminf(fmaxf(cx0 + 0.5f * w, 0.0f), 1.0f);
        boxes[(size_t)b * K_PRE + r] = o;
    }
}

__global__ __launch_bounds__(256) void k_matrix(const float4* __restrict__ boxes,
                                                uint32_t* __restrict__ mask) {
    const int blk = blockIdx.x;
    const int b = blk >> 10;
    const int tile = blk & 1023;
    const int ti = tile >> 5, tj = tile & 31;
    __shared__ float4 rb[64], cb[64];
    __shared__ uint32_t wbits[128];
    const float4* bx = boxes + (size_t)b * K_PRE;
    const int t = threadIdx.x;
    if (t < 64) rb[t] = bx[ti * 64 + t];
    else if (t < 128) cb[t - 64] = bx[tj * 64 + (t - 64)];
    if (t < 128) wbits[t] = 0;
    __syncthreads();
    const int r = t >> 2;
    const int cq = t & 3;
    const float4 a = rb[r];
    const float areaA = (a.z - a.x) * (a.w - a.y);
    uint32_t bits = 0;
#pragma unroll
    for (int jj = 0; jj < 16; ++jj) {
        const float4 cc = cb[cq * 16 + jj];
        const float yy1 = fmaxf(a.x, cc.x), xx1 = fmaxf(a.y, cc.y);
        const float yy2 = fminf(a.z, cc.z), xx2 = fminf(a.w, cc.w);
        const float inter = fmaxf(yy2 - yy1, 0.0f) * fmaxf(xx2 - xx1, 0.0f);
        const float areaC = (cc.z - cc.x) * (cc.w - cc.y);
        const float uni = fmaxf(areaA + areaC - inter, 1e-8f);
        if (inter / uni > NMS_THR) bits |= (1u << jj);
    }
    atomicOr(&wbits[r * 2 + (cq >> 1)], bits << ((cq & 1) * 16));
    __syncthreads();
    if (t < 128) {
        const int rr = t >> 1, ww = t & 1;
        mask[((size_t)b * PREFIX + ti * 64 + rr) * 64 + tj * 2 + ww] = wbits[rr * 2 + ww];
    }
}

// Greedy NMS bit-scan over the 2048x2048 suppression matrix.
__global__ __launch_bounds__(256) void k_greedy(const uint32_t* __restrict__ mask,
                                                uint32_t* meta, uint32_t* __restrict__ kept_idx) {
    __shared__ uint32_t lbuf[2][256 * 64];   // 2 x 64 KB
    __shared__ uint32_t skept[8];
    const int b = blockIdx.x;
    const int lane = threadIdx.x & 63;
    const int wave = threadIdx.x >> 6;
    const uint32_t* mrow = mask + (size_t)b * PREFIX * 64;

    {
        const uint4* s4 = (const uint4*)mrow;
        uint4* d4 = (uint4*)lbuf[0];
        for (int idx = threadIdx.x; idx < 4096; idx += 256) d4[idx] = s4[idx];
    }
    __syncthreads();

    uint32_t supp = 0;   // lane l: suppression bits for columns [32l, 32l+32)
    uint32_t kept = 0;

    for (int c = 0; c < PREFIX / 256; ++c) {
        if (wave > 0) {
            if (c + 1 < PREFIX / 256) {
                const uint4* s4 = (const uint4*)(mrow + (size_t)(c + 1) * 256 * 64);
                uint4* d4 = (uint4*)lbuf[(c + 1) & 1];
                for (int idx = threadIdx.x - 64; idx < 4096; idx += 192) d4[idx] = s4[idx];
            }
        } else {
            const uint32_t* L = lbuf[c & 1];
            for (int g = 0; g < 8; ++g) {
                if (kept >= NPROP) break;
                const int grow = c * 256 + g * 32;
                const int w = grow >> 5;
                uint32_t rbuf[32];
#pragma unroll
                for (int q = 0; q < 32; ++q) rbuf[q] = L[(g * 32 + q) * 64 + lane];
                uint32_t sw = __builtin_amdgcn_readlane(supp, w);
#pragma unroll
                for (int q = 0; q < 32; ++q) {
                    if (kept < NPROP && !((sw >> q) & 1u)) {
                        if (lane == 0) kept_idx[(size_t)b * NPROP + kept] = (uint32_t)(grow + q);
                        supp |= rbuf[q];
                        sw |= __builtin_amdgcn_readlane(rbuf[q], w);
                        ++kept;
                    }
                }
            }
            if (lane == 0) skept[c] = kept;
        }
        __syncthreads();
        if (skept[c] >= NPROP) break;
    }
    if (wave == 0 && lane == 0) meta[MT_KEPT + b] = kept;
}

__global__ __launch_bounds__(1024) void k_finish(const float4* __restrict__ boxes,
        uint32_t* meta, uint32_t* kept_idx, float4* __restrict__ out) {
    const int b = blockIdx.x;
    const float4* bx = boxes + (size_t)b * K_PRE;
    __shared__ float4 kb[NPROP];
    __shared__ uint32_t sflag;
    uint32_t kept = meta[MT_KEPT + b];
    if (kept < NPROP) {
        for (uint32_t k = threadIdx.x; k < kept; k += 1024)
            kb[k] = bx[kept_idx[(size_t)b * NPROP + k]];
        __syncthreads();
        for (int i = PREFIX; i < K_PRE && kept < NPROP; ++i) {
            if (threadIdx.x == 0) sflag = 0;
            __syncthreads();
            const float4 c = bx[i];
            const float areaC = (c.z - c.x) * (c.w - c.y);
            bool sup = false;
            for (uint32_t k = threadIdx.x; k < kept; k += 1024) {
                const float4 a = kb[k];
                const float yy1 = fmaxf(c.x, a.x), xx1 = fmaxf(c.y, a.y);
                const float yy2 = fminf(c.z, a.z), xx2 = fminf(c.w, a.w);
                const float inter = fmaxf(yy2 - yy1, 0.0f) * fmaxf(xx2 - xx1, 0.0f);
                const float areaA = (a.z - a.x) * (a.w - a.y);
                const float uni = fmaxf(areaC + areaA - inter, 1e-8f);
                if (inter / uni > NMS_THR) { sup = true; break; }
            }
            if (sup) atomicOr(&sflag, 1u);
            __syncthreads();
            if (sflag == 0) {
                if (threadIdx.x == 0) {
                    kept_idx[(size_t)b * NPROP + kept] = (uint32_t)i;
                    kb[kept] = c;
                }
                ++kept;
            }
            __syncthreads();
        }
        if (threadIdx.x == 0) meta[MT_KEPT + b] = kept;
    }
    __syncthreads();
    for (uint32_t k = threadIdx.x; k < NPROP; k += 1024) {
        float4 v = make_float4(0.f, 0.f, 0.f, 0.f);
        if (k < kept) v = bx[kept_idx[(size_t)b * NPROP + k]];
        out[(size_t)b * NPROP + k] = v;
    }
}

extern "C" void kernel_launch(void* const* d_in, const int* in_sizes, int n_in,
                              void* d_out, int out_size, void* d_ws, size_t ws_size,
                              hipStream_t stream) {
    const float4* probs4 = (const float4*)d_in[0];
    const float4* bbox   = (const float4*)d_in[1];
    const float4* anch   = (const float4*)d_in[2];
    char* ws = (char*)d_ws;
    if (ws_size < (size_t)WS_NEED) return;
    uint32_t* hist1 = (uint32_t*)(ws + HIST1_OFF);
    uint32_t* hist2 = (uint32_t*)(ws + HIST2_OFF);
    uint32_t* meta  = (uint32_t*)(ws + META_OFF);
    uint64_t* cand  = (uint64_t*)(ws + CAND_OFF);
    float4*   boxes = (float4*)(ws + BOXES_OFF);
    uint32_t* mask  = (uint32_t*)(ws + MASK_OFF);
    uint32_t* kidx  = (uint32_t*)(ws + KIDX_OFF);

    k_zero<<<dim3((BATCH * (NB1 + NB2) + 255) / 256), dim3(256), 0, stream>>>(hist1);
    k_hist<<<dim3(512), dim3(256), 0, stream>>>(probs4, hist1);
    k_thresh<<<dim3(BATCH), dim3(256), 0, stream>>>(hist1, meta);
    k_hist2<<<dim3(2048), dim3(256), 0, stream>>>(probs4, meta, hist2);
    k_thresh2<<<dim3(BATCH), dim3(256), 0, stream>>>(hist2, meta);
    k_compact<<<dim3(2048), dim3(256), 0, stream>>>(probs4, meta, meta, cand);
    k_sortdecode<<<dim3(BATCH), dim3(1024), 0, stream>>>(cand, meta, bbox, anch, boxes);
    k_matrix<<<dim3(BATCH * 1024), dim3(256), 0, stream>>>(boxes, mask);
    k_greedy<<<dim3(BATCH), dim3(256), 0, stream>>>(mask, meta, kidx);
    k_finish<<<dim3(BATCH), dim3(1024), 0, stream>>>(boxes, meta, kidx, (float4*)d_out);
}